// Round 7
// baseline (653.049 us; speedup 1.0000x reference)
//
#include <hip/hip_runtime.h>

// Fused 64-layer GRU (H=64, T=2, B=16384) -- MFMA split-bf16, pipelined.
// Only batch rows 8192..16383 feed the output (verified rounds 1-3, absmax 0).
//
// Round-7 = round-4 resubmit (three consecutive broker timeouts; never ran).
//  * 512 blocks x 512 threads, 16 batch rows/block -> 2 blocks/CU, 16 waves/CU.
//  * One barrier per layer: phase P_l = { t1 of layer l  +  t0 of layer l+1 }.
//    t0 chain depends only on t0 of the previous layer, so it runs one layer
//    ahead; the 3 GEMMs per phase (gi1, gh1, gi0') are mutually independent.
//  * Waves 0-3 (t1-path): gi1 = Wi(l)*X1(l-1), gh1 = Wh(l)*h0(l), t1 gates.
//    Waves 4-7 (t0-path): gi0 = Wi(l+1)*h0(l), t0 gates -> h0(l+1).
//    Each wave owns cols jq*16..+15 (all 3 gates) of all 16 rows -> gate math
//    fully in-register, no cross-wave gate exchange.
//  * MFMA operands SWAPPED vs round 3: A = weights (M = 16 gate-cols),
//    B = hidden state (N = 16 batch rows). C layout (m89) gives each lane
//    (1 batch row, 4 consecutive gate-cols) -> h writes are b64 (bf16 hi/lo)
//    and b128 (fp32), all fragment LDS reads 2-way banked (free per m136).
//  * Split-bf16 GEMMs (hi*hi + lo*hi + hi*lo), gates/biases/z*h0 in fp32.

typedef __attribute__((ext_vector_type(8))) short short8;
typedef __attribute__((ext_vector_type(4))) short short4v;
typedef __attribute__((ext_vector_type(4))) float f32x4;

#define MFMA16(a, b, c) __builtin_amdgcn_mfma_f32_16x16x32_bf16((a), (b), (c), 0, 0, 0)

namespace {

constexpr int kH    = 64;
constexpr int kL    = 64;
constexpr int kB    = 16384;
constexpr int kRPB  = 16;                 // rows per block
constexpr int kGrid = (kB / 2) / kRPB;    // 512 blocks
constexpr int kBlk  = 512;                // 8 waves
constexpr int kXP   = 72;                 // X pad (shorts; 144 B row stride)
constexpr int kH0P  = 68;                 // H0f pad (floats; 272 B row stride)

// d_ws layout: shorts region then float region.
constexpr size_t nWi       = (size_t)63 * 192 * 64;   // Wih layers 1..63 (idx l-1)
constexpr size_t nWh       = (size_t)64 * 192 * 64;   // Whh layers 0..63
constexpr size_t oWiHi     = 0;
constexpr size_t oWiLo     = oWiHi + nWi;
constexpr size_t oWhHi     = oWiLo + nWi;
constexpr size_t oWhLo     = oWhHi + nWh;
constexpr size_t oShortEnd = oWhLo + nWh;             // 3,121,152 shorts
constexpr size_t nB1       = (size_t)64 * 192;
constexpr size_t oBi       = 0;                       // floats, after short region
constexpr size_t oBh       = nB1;

__device__ __forceinline__ unsigned short rne_bf16(float f) {
    unsigned u = __float_as_uint(f);
    return (unsigned short)((u + 0x7FFFu + ((u >> 16) & 1u)) >> 16);
}
__device__ __forceinline__ float bf2f(unsigned short s) {
    return __uint_as_float(((unsigned)s) << 16);
}
__device__ __forceinline__ float sigm(float v) {
    float e = __expf(-v);
    return __builtin_amdgcn_rcpf(1.0f + e);
}
__device__ __forceinline__ float tanh_fast(float v) {
    float e = __expf(-2.0f * v);
    return (1.0f - e) * __builtin_amdgcn_rcpf(1.0f + e);
}

} // namespace

// ---------------------------------------------------------------------------
// Prep: fp32 weights -> reordered split-bf16 in ws (4 k per thread); biases
// reordered fp32. n-reorder: n = jq*48 + g*16 + jc <-> orig row = g*64+jq*16+jc.
extern "C" __global__ void gru_prep(const float* __restrict__ Whh0,
                                    const float* __restrict__ bih0,
                                    const float* __restrict__ bhh0,
                                    const float* __restrict__ WihL,
                                    const float* __restrict__ WhhL,
                                    const float* __restrict__ bihL,
                                    const float* __restrict__ bhhL,
                                    short* __restrict__ wsS,
                                    float* __restrict__ wsF)
{
    int idx = (int)blockIdx.x * 256 + (int)threadIdx.x;
    const int nWi4 = 63 * 192 * 16;   // float4 granules
    const int nWh4 = 64 * 192 * 16;
    const int nBT  = 64 * 192;

    if (idx < nWi4) {
        const int li  = idx / (192 * 16);
        const int rem = idx % (192 * 16);
        const int n = rem >> 4, k4 = rem & 15;
        const int jq = n / 48, g = (n % 48) / 16, jc = n % 16;
        const int row = g * 64 + jq * 16 + jc;
        const f32x4 w = *reinterpret_cast<const f32x4*>(
            WihL + (size_t)li * 12288 + row * 64 + k4 * 4);
        short4v hi, lo;
        #pragma unroll
        for (int e = 0; e < 4; ++e) {
            const unsigned short h = rne_bf16(w[e]);
            hi[e] = (short)h;
            lo[e] = (short)rne_bf16(w[e] - bf2f(h));
        }
        const size_t off = (size_t)li * 12288 + n * 64 + k4 * 4;
        *reinterpret_cast<short4v*>(wsS + oWiHi + off) = hi;
        *reinterpret_cast<short4v*>(wsS + oWiLo + off) = lo;
        return;
    }
    idx -= nWi4;
    if (idx < nWh4) {
        const int li  = idx / (192 * 16);
        const int rem = idx % (192 * 16);
        const int n = rem >> 4, k4 = rem & 15;
        const int jq = n / 48, g = (n % 48) / 16, jc = n % 16;
        const int row = g * 64 + jq * 16 + jc;
        const float* src = (li == 0) ? (Whh0 + row * 64 + k4 * 4)
                                     : (WhhL + (size_t)(li - 1) * 12288 + row * 64 + k4 * 4);
        const f32x4 w = *reinterpret_cast<const f32x4*>(src);
        short4v hi, lo;
        #pragma unroll
        for (int e = 0; e < 4; ++e) {
            const unsigned short h = rne_bf16(w[e]);
            hi[e] = (short)h;
            lo[e] = (short)rne_bf16(w[e] - bf2f(h));
        }
        const size_t off = (size_t)li * 12288 + n * 64 + k4 * 4;
        *reinterpret_cast<short4v*>(wsS + oWhHi + off) = hi;
        *reinterpret_cast<short4v*>(wsS + oWhLo + off) = lo;
        return;
    }
    idx -= nWh4;
    if (idx < nBT) {
        const int li = idx / 192, n = idx % 192;
        const int jq = n / 48, g = (n % 48) / 16, jc = n % 16;
        const int row = g * 64 + jq * 16 + jc;
        wsF[oBi + idx] = (li == 0) ? bih0[row] : bihL[(size_t)(li - 1) * 192 + row];
        return;
    }
    idx -= nBT;
    if (idx < nBT) {
        const int li = idx / 192, n = idx % 192;
        const int jq = n / 48, g = (n % 48) / 16, jc = n % 16;
        const int row = g * 64 + jq * 16 + jc;
        wsF[oBh + idx] = (li == 0) ? bhh0[row] : bhhL[(size_t)(li - 1) * 192 + row];
        return;
    }
}

// ---------------------------------------------------------------------------
extern "C" __global__ __launch_bounds__(kBlk, 4)
void gru_mfma(const float* __restrict__ x,
              const float* __restrict__ Wih0,
              const float* __restrict__ Wf,
              const float* __restrict__ bfp,
              const short* __restrict__ wsS,
              const float* __restrict__ wsF,
              float* __restrict__ out)
{
    __shared__ __align__(16) short X0hi[2][kRPB][kXP];
    __shared__ __align__(16) short X0lo[2][kRPB][kXP];
    __shared__ __align__(16) short X1hi[2][kRPB][kXP];
    __shared__ __align__(16) short X1lo[2][kRPB][kXP];
    __shared__ __align__(16) float H0f[2][kRPB][kH0P];

    const int tid  = (int)threadIdx.x;
    const int lane = tid & 63;
    const int l15  = lane & 15;                                  // batch row
    const int l4   = lane >> 4;                                  // 0..3
    const int jw   = __builtin_amdgcn_readfirstlane(tid >> 6);   // wave 0..7
    const int jq   = jw & 3;                                     // col-quarter
    const int wt   = jw >> 2;                                    // 0:t1-path 1:t0-path
    const int grow = kB / 2 + (int)blockIdx.x * kRPB + l15;      // global row

    const float xv0 = x[grow * 2 + 0];
    const float xv1 = x[grow * 2 + 1];

    const int col4  = jq * 16 + l4 * 4;                // lane's first col
    const int wbase = (jq * 48 + l15) * 64 + l4 * 8;   // weight frag base (+g*1024+ks*32)
    const int xoff  = l4 * 8;                          // X frag k offset (+ks*32)

    // ---------------- prologue: h0(0) from x(t=0), F = 1 ----------------
    if (wt == 1) {
        const float* biL = wsF + oBi + jq * 48 + l4 * 4;   // layer 0
        const float* bhL = wsF + oBh + jq * 48 + l4 * 4;
        const f32x4 w0 = *reinterpret_cast<const f32x4*>(Wih0 + 0 * 64 + col4);
        const f32x4 w1 = *reinterpret_cast<const f32x4*>(Wih0 + 1 * 64 + col4);
        const f32x4 w2 = *reinterpret_cast<const f32x4*>(Wih0 + 2 * 64 + col4);
        const f32x4 bi0 = *reinterpret_cast<const f32x4*>(biL);
        const f32x4 bi1 = *reinterpret_cast<const f32x4*>(biL + 16);
        const f32x4 bi2 = *reinterpret_cast<const f32x4*>(biL + 32);
        const f32x4 bh0 = *reinterpret_cast<const f32x4*>(bhL);
        const f32x4 bh1 = *reinterpret_cast<const f32x4*>(bhL + 16);
        const f32x4 bh2 = *reinterpret_cast<const f32x4*>(bhL + 32);
        short4v ohi, olo; f32x4 fh;
        #pragma unroll
        for (int r = 0; r < 4; ++r) {
            const float rr = sigm(w0[r] * xv0 + bi0[r] + bh0[r]);
            const float zz = sigm(w1[r] * xv0 + bi1[r] + bh1[r]);
            const float nn = tanh_fast(w2[r] * xv0 + bi2[r] + rr * bh2[r]);
            const float h0 = (1.0f - zz) * nn;
            fh[r] = h0;
            const unsigned short h = rne_bf16(h0);
            ohi[r] = (short)h;
            olo[r] = (short)rne_bf16(h0 - bf2f(h));
        }
        *reinterpret_cast<f32x4*>(&H0f[0][l15][col4])   = fh;
        *reinterpret_cast<short4v*>(&X0hi[0][l15][col4]) = ohi;
        *reinterpret_cast<short4v*>(&X0lo[0][l15][col4]) = olo;
    }
    __syncthreads();

    // ---------------- pipelined layer loop: one barrier per phase ----------
    #pragma unroll 1
    for (int l = 0; l < kL; ++l) {
        const int rb = l & 1, wb = rb ^ 1;

        if (wt == 0) {
            // ======== t1 path: gi1 = Wi(l)*X1(l-1), gh1 = Wh(l)*h0(l) ======
            f32x4 ai[3], ah[3];
            #pragma unroll
            for (int g = 0; g < 3; ++g) {
                ai[g] = f32x4{0.f, 0.f, 0.f, 0.f};
                ah[g] = f32x4{0.f, 0.f, 0.f, 0.f};
            }

            if (l == 0) {
                // F = 1: gi1 directly from x(t=1)
                const f32x4 w0 = *reinterpret_cast<const f32x4*>(Wih0 + 0 * 64 + col4);
                const f32x4 w1 = *reinterpret_cast<const f32x4*>(Wih0 + 1 * 64 + col4);
                const f32x4 w2 = *reinterpret_cast<const f32x4*>(Wih0 + 2 * 64 + col4);
                #pragma unroll
                for (int r = 0; r < 4; ++r) {
                    ai[0][r] = w0[r] * xv1;
                    ai[1][r] = w1[r] * xv1;
                    ai[2][r] = w2[r] * xv1;
                }
            } else {
                short8 xh[2], xl[2];
                #pragma unroll
                for (int ks = 0; ks < 2; ++ks) {
                    xh[ks] = *reinterpret_cast<const short8*>(&X1hi[rb][l15][ks * 32 + xoff]);
                    xl[ks] = *reinterpret_cast<const short8*>(&X1lo[rb][l15][ks * 32 + xoff]);
                }
                const short* WiH = wsS + oWiHi + (size_t)(l - 1) * 12288;
                const short* WiL = wsS + oWiLo + (size_t)(l - 1) * 12288;
                #pragma unroll
                for (int g = 0; g < 3; ++g)
                    #pragma unroll
                    for (int ks = 0; ks < 2; ++ks) {
                        const short8 wh_ = *reinterpret_cast<const short8*>(WiH + wbase + g * 1024 + ks * 32);
                        const short8 wl_ = *reinterpret_cast<const short8*>(WiL + wbase + g * 1024 + ks * 32);
                        ai[g] = MFMA16(wh_, xh[ks], ai[g]);
                        ai[g] = MFMA16(wl_, xh[ks], ai[g]);
                        ai[g] = MFMA16(wh_, xl[ks], ai[g]);
                    }
            }
            {
                short8 hh[2], hl[2];
                #pragma unroll
                for (int ks = 0; ks < 2; ++ks) {
                    hh[ks] = *reinterpret_cast<const short8*>(&X0hi[rb][l15][ks * 32 + xoff]);
                    hl[ks] = *reinterpret_cast<const short8*>(&X0lo[rb][l15][ks * 32 + xoff]);
                }
                const short* WhH = wsS + oWhHi + (size_t)l * 12288;
                const short* WhL = wsS + oWhLo + (size_t)l * 12288;
                #pragma unroll
                for (int g = 0; g < 3; ++g)
                    #pragma unroll
                    for (int ks = 0; ks < 2; ++ks) {
                        const short8 wh_ = *reinterpret_cast<const short8*>(WhH + wbase + g * 1024 + ks * 32);
                        const short8 wl_ = *reinterpret_cast<const short8*>(WhL + wbase + g * 1024 + ks * 32);
                        ah[g] = MFMA16(wh_, hh[ks], ah[g]);
                        ah[g] = MFMA16(wl_, hh[ks], ah[g]);
                        ah[g] = MFMA16(wh_, hl[ks], ah[g]);
                    }
            }
            // t1 gates, fully in-register
            const float* biL = wsF + oBi + (size_t)l * 192 + jq * 48 + l4 * 4;
            const float* bhL = wsF + oBh + (size_t)l * 192 + jq * 48 + l4 * 4;
            const f32x4 bi0 = *reinterpret_cast<const f32x4*>(biL);
            const f32x4 bi1 = *reinterpret_cast<const f32x4*>(biL + 16);
            const f32x4 bi2 = *reinterpret_cast<const f32x4*>(biL + 32);
            const f32x4 bh0 = *reinterpret_cast<const f32x4*>(bhL);
            const f32x4 bh1 = *reinterpret_cast<const f32x4*>(bhL + 16);
            const f32x4 bh2 = *reinterpret_cast<const f32x4*>(bhL + 32);
            const f32x4 h0v = *reinterpret_cast<const f32x4*>(&H0f[rb][l15][col4]);
            short4v ohi, olo;
            #pragma unroll
            for (int r = 0; r < 4; ++r) {
                const float rr = sigm(ai[0][r] + bi0[r] + ah[0][r] + bh0[r]);
                const float zz = sigm(ai[1][r] + bi1[r] + ah[1][r] + bh1[r]);
                const float nn = tanh_fast(ai[2][r] + bi2[r] + rr * (ah[2][r] + bh2[r]));
                const float h1 = (1.0f - zz) * nn + zz * h0v[r];
                const unsigned short h = rne_bf16(h1);
                ohi[r] = (short)h;
                olo[r] = (short)rne_bf16(h1 - bf2f(h));
            }
            *reinterpret_cast<short4v*>(&X1hi[wb][l15][col4]) = ohi;
            *reinterpret_cast<short4v*>(&X1lo[wb][l15][col4]) = olo;
        } else if (l < kL - 1) {
            // ======== t0 path: gi0 = Wi(l+1)*h0(l) -> h0(l+1) =============
            f32x4 a0[3];
            #pragma unroll
            for (int g = 0; g < 3; ++g) a0[g] = f32x4{0.f, 0.f, 0.f, 0.f};
            short8 hh[2], hl[2];
            #pragma unroll
            for (int ks = 0; ks < 2; ++ks) {
                hh[ks] = *reinterpret_cast<const short8*>(&X0hi[rb][l15][ks * 32 + xoff]);
                hl[ks] = *reinterpret_cast<const short8*>(&X0lo[rb][l15][ks * 32 + xoff]);
            }
            const short* WiH = wsS + oWiHi + (size_t)l * 12288;   // layer l+1
            const short* WiL = wsS + oWiLo + (size_t)l * 12288;
            #pragma unroll
            for (int g = 0; g < 3; ++g)
                #pragma unroll
                for (int ks = 0; ks < 2; ++ks) {
                    const short8 wh_ = *reinterpret_cast<const short8*>(WiH + wbase + g * 1024 + ks * 32);
                    const short8 wl_ = *reinterpret_cast<const short8*>(WiL + wbase + g * 1024 + ks * 32);
                    a0[g] = MFMA16(wh_, hh[ks], a0[g]);
                    a0[g] = MFMA16(wl_, hh[ks], a0[g]);
                    a0[g] = MFMA16(wh_, hl[ks], a0[g]);
                }
            const float* biL = wsF + oBi + (size_t)(l + 1) * 192 + jq * 48 + l4 * 4;
            const float* bhL = wsF + oBh + (size_t)(l + 1) * 192 + jq * 48 + l4 * 4;
            const f32x4 bi0 = *reinterpret_cast<const f32x4*>(biL);
            const f32x4 bi1 = *reinterpret_cast<const f32x4*>(biL + 16);
            const f32x4 bi2 = *reinterpret_cast<const f32x4*>(biL + 32);
            const f32x4 bh0 = *reinterpret_cast<const f32x4*>(bhL);
            const f32x4 bh1 = *reinterpret_cast<const f32x4*>(bhL + 16);
            const f32x4 bh2 = *reinterpret_cast<const f32x4*>(bhL + 32);
            short4v ohi, olo; f32x4 fh;
            #pragma unroll
            for (int r = 0; r < 4; ++r) {
                const float rr = sigm(a0[0][r] + bi0[r] + bh0[r]);
                const float zz = sigm(a0[1][r] + bi1[r] + bh1[r]);
                const float nn = tanh_fast(a0[2][r] + bi2[r] + rr * bh2[r]);
                const float h0 = (1.0f - zz) * nn;
                fh[r] = h0;
                const unsigned short h = rne_bf16(h0);
                ohi[r] = (short)h;
                olo[r] = (short)rne_bf16(h0 - bf2f(h));
            }
            *reinterpret_cast<f32x4*>(&H0f[wb][l15][col4])   = fh;
            *reinterpret_cast<short4v*>(&X0hi[wb][l15][col4]) = ohi;
            *reinterpret_cast<short4v*>(&X0lo[wb][l15][col4]) = olo;
        }
        __syncthreads();
    }

    // ---------------- final linear --------------------------------------
    // h0(63) sits in H0f[1] (exact fp32, written by P_62); X1(63) in X1[0].
    if (tid < 32) {
        const int row = tid & 15, t = tid >> 4;
        float a = 0.0f;
        if (t == 0) {
            #pragma unroll
            for (int c = 0; c < 16; ++c) {
                const f32x4 hv = *reinterpret_cast<const f32x4*>(&H0f[1][row][c * 4]);
                #pragma unroll
                for (int e = 0; e < 4; ++e) a = fmaf(Wf[c * 4 + e], hv[e], a);
            }
        } else {
            #pragma unroll
            for (int c = 0; c < 8; ++c) {
                const short8 hv = *reinterpret_cast<const short8*>(&X1hi[0][row][c * 8]);
                const short8 lv = *reinterpret_cast<const short8*>(&X1lo[0][row][c * 8]);
                #pragma unroll
                for (int e = 0; e < 8; ++e)
                    a = fmaf(Wf[c * 8 + e],
                             bf2f((unsigned short)hv[e]) + bf2f((unsigned short)lv[e]), a);
            }
        }
        out[2 * ((int)blockIdx.x * kRPB + row) + t] = a + bfp[0];
    }
}

// ---------------------------------------------------------------------------
extern "C" void kernel_launch(void* const* d_in, const int* in_sizes, int n_in,
                              void* d_out, int out_size, void* d_ws, size_t ws_size,
                              hipStream_t stream) {
    const float* x    = (const float*)d_in[0];
    const float* Wih0 = (const float*)d_in[1];
    const float* Whh0 = (const float*)d_in[2];
    const float* bih0 = (const float*)d_in[3];
    const float* bhh0 = (const float*)d_in[4];
    const float* WihL = (const float*)d_in[5];
    const float* WhhL = (const float*)d_in[6];
    const float* bihL = (const float*)d_in[7];
    const float* bhhL = (const float*)d_in[8];
    const float* Wf   = (const float*)d_in[9];
    const float* bfp  = (const float*)d_in[10];

    short* wsS = (short*)d_ws;
    float* wsF = (float*)((char*)d_ws + oShortEnd * sizeof(short));

    // prep granules: 193536 (Wi f4) + 196608 (Wh f4) + 2*12288 (biases) = 414720
    gru_prep<<<dim3(414720 / 256), dim3(256), 0, stream>>>(
        Whh0, bih0, bhh0, WihL, WhhL, bihL, bhhL, wsS, wsF);

    gru_mfma<<<dim3(kGrid), dim3(kBlk), 0, stream>>>(
        x, Wih0, Wf, bfp, wsS, wsF, (float*)d_out);
}